// Round 2
// baseline (4931.438 us; speedup 1.0000x reference)
//
#include <hip/hip_runtime.h>
#include <cstddef>

#define B 32
#define T_ENC 512
#define T_DEC 32
#define E 256
#define VOCAB 32000
#define SOS 1

typedef __attribute__((ext_vector_type(8))) short short8;   // 8 x bf16
typedef __attribute__((ext_vector_type(4))) float floatx4;  // MFMA acc

// ---------------- workspace layout (float offsets) ----------------
static const size_t OFF_ENCWM = 0;                                   // B*T_ENC*E
static const size_t OFF_ENCWC = OFF_ENCWM + (size_t)B * T_ENC * E;   // B*T_ENC*E
static const size_t OFF_WEFFM = OFF_ENCWC + (size_t)B * T_ENC * E;   // E
static const size_t OFF_WEFFC = OFF_WEFFM + E;                       // E
static const size_t OFF_H     = OFF_WEFFC + E;                       // B*E
static const size_t OFF_HVM   = OFF_H + (size_t)B * E;               // B*E
static const size_t OFF_HVC   = OFF_HVM + (size_t)B * E;             // B*E
static const size_t OFF_P     = OFF_HVC + (size_t)B * E;             // B*T_ENC
static const size_t OFF_EC    = OFF_P + (size_t)B * T_ENC;           // B*T_ENC
static const size_t OFF_ALPHA = OFF_EC + (size_t)B * T_ENC;          // B*T_ENC
static const size_t OFF_XIH   = OFF_ALPHA + (size_t)B * T_ENC;       // T_DEC*B*E floats
static const size_t OFF_ATTNB = OFF_XIH + (size_t)T_DEC * B * E;     // T_DEC*B*E ushorts -> /2 floats
static const size_t OFF_WPBF  = OFF_ATTNB + (size_t)T_DEC * B * E / 2; // VOCAB*E ushorts -> /2 floats
// total ~13.0M floats ~= 52 MB

__device__ __forceinline__ float wave_reduce(float s) {
  s += __shfl_down(s, 32, 64); s += __shfl_down(s, 16, 64); s += __shfl_down(s, 8, 64);
  s += __shfl_down(s, 4, 64);  s += __shfl_down(s, 2, 64);  s += __shfl_down(s, 1, 64);
  return s;
}

__device__ __forceinline__ unsigned short f2bf(float f) {
  unsigned int u = __float_as_uint(f);
  u = (u + 0x7fffu + ((u >> 16) & 1u)) >> 16;   // RNE
  return (unsigned short)u;
}

// ---------------- w_eff = (g/||vv||)*vv ----------------
__global__ __launch_bounds__(256) void weff_kernel(
    const float* __restrict__ vvm, const float* __restrict__ gm, float* __restrict__ w_effm,
    const float* __restrict__ vvc, const float* __restrict__ gc, float* __restrict__ w_effc)
{
  const float* vv = blockIdx.x ? vvc : vvm;
  const float* g  = blockIdx.x ? gc  : gm;
  float* out      = blockIdx.x ? w_effc : w_effm;
  __shared__ float red[256];
  int tid = threadIdx.x;
  float v = vv[tid];
  red[tid] = v * v;
  __syncthreads();
  for (int off = 128; off > 0; off >>= 1) {
    if (tid < off) red[tid] += red[tid + off];
    __syncthreads();
  }
  float norm = sqrtf(red[0]);
  out[tid] = (g[0] / norm) * v;
}

// ---------------- init alpha0 + copy h0 ----------------
__global__ __launch_bounds__(256) void init_kernel(
    float* __restrict__ alpha, float* __restrict__ h_g, const float* __restrict__ h0)
{
  int i = blockIdx.x * 256 + threadIdx.x;   // grid 64 -> 16384 threads
  alpha[i] = ((i & (T_ENC - 1)) == 0) ? 1.0f : 0.0f;
  if (i < B * E) h_g[i] = h0[i];
}

// ---------------- gather embeddings for all steps: embX[r,:] = emb[tok(r)], r = s*B+b ----
__global__ __launch_bounds__(256) void gather_emb(
    const int* __restrict__ dec, const float* __restrict__ emb, float* __restrict__ embX)
{
  int r = blockIdx.x, d = threadIdx.x;
  int s = r >> 5, b = r & 31;
  int tok = (s == 0) ? SOS : dec[b * T_DEC + s - 1];
  embX[(size_t)r * E + d] = emb[(size_t)tok * E + d];
}

// ---------------- f32 -> bf16 convert (4 per thread) ----------------
__global__ __launch_bounds__(256) void cvt_bf16(
    const float* __restrict__ src, unsigned short* __restrict__ dst)
{
  size_t i = ((size_t)blockIdx.x * 256 + threadIdx.x) * 4;
  float4 v = *(const float4*)(src + i);
  ushort4 o;
  o.x = f2bf(v.x); o.y = f2bf(v.y); o.z = f2bf(v.z); o.w = f2bf(v.w);
  *(ushort4*)(dst + i) = o;
}

// ---------------- Y[r,n] = bias[n] + sum_k A[r,k]*W[n,k] (f32 VALU GEMM) ----------------
__global__ __launch_bounds__(256) void gemm_xwt(
    const float* __restrict__ A, const float* __restrict__ W,
    const float* __restrict__ bias, float* __restrict__ Y,
    int M, int N, int K)
{
  __shared__ float As[64][68];
  __shared__ float Ws[64][68];
  const int tid = threadIdx.x;
  const int tx = tid & 15, ty = tid >> 4;
  const int row0 = blockIdx.y * 64, col0 = blockIdx.x * 64;
  float acc[4][4];
#pragma unroll
  for (int i = 0; i < 4; i++)
#pragma unroll
    for (int j = 0; j < 4; j++) acc[i][j] = 0.f;

  for (int k0 = 0; k0 < K; k0 += 64) {
#pragma unroll
    for (int s = 0; s < 4; s++) {
      int i = (s << 4) + ty;
      int j = tx << 2;
      float4 av = *(const float4*)(A + (size_t)(row0 + i) * K + k0 + j);
      As[j][i] = av.x; As[j + 1][i] = av.y; As[j + 2][i] = av.z; As[j + 3][i] = av.w;
      float4 wv = *(const float4*)(W + (size_t)(col0 + i) * K + k0 + j);
      Ws[j][i] = wv.x; Ws[j + 1][i] = wv.y; Ws[j + 2][i] = wv.z; Ws[j + 3][i] = wv.w;
    }
    __syncthreads();
#pragma unroll
    for (int kk = 0; kk < 64; kk++) {
      const float4 af = *(const float4*)&As[kk][ty << 2];
      const float4 bf = *(const float4*)&Ws[kk][tx << 2];
      acc[0][0] += af.x * bf.x; acc[0][1] += af.x * bf.y; acc[0][2] += af.x * bf.z; acc[0][3] += af.x * bf.w;
      acc[1][0] += af.y * bf.x; acc[1][1] += af.y * bf.y; acc[1][2] += af.y * bf.z; acc[1][3] += af.y * bf.w;
      acc[2][0] += af.z * bf.x; acc[2][1] += af.z * bf.y; acc[2][2] += af.z * bf.z; acc[2][3] += af.z * bf.w;
      acc[3][0] += af.w * bf.x; acc[3][1] += af.w * bf.y; acc[3][2] += af.w * bf.z; acc[3][3] += af.w * bf.w;
    }
    __syncthreads();
  }
  const float4 bv = *(const float4*)(bias + col0 + (tx << 2));
#pragma unroll
  for (int i = 0; i < 4; i++) {
    float4 o;
    o.x = acc[i][0] + bv.x; o.y = acc[i][1] + bv.y;
    o.z = acc[i][2] + bv.z; o.w = acc[i][3] + bv.w;
    *(float4*)(Y + (size_t)(row0 + (ty << 2) + i) * N + col0 + (tx << 2)) = o;
  }
}

// ---------------- RNN step: h=tanh(Xih+b_hh+h@W_hh.T), hVm=h@Vm.T, hVc=h@Vc.T ----------
// one block per b; wave-split-K (coalesced weight rows + shuffle reduce)
__global__ __launch_bounds__(256) void rnn_step(
    const float* __restrict__ Xih, const float* __restrict__ W_hh,
    const float* __restrict__ b_hh,
    const float* __restrict__ Vm, const float* __restrict__ Vc,
    float* __restrict__ h_g, float* __restrict__ hVm, float* __restrict__ hVc,
    int step)
{
  __shared__ float hs[256], hn[256];
  const int b = blockIdx.x, tid = threadIdx.x;
  const int wave = tid >> 6, lane = tid & 63;
  hs[tid] = h_g[(size_t)b * E + tid];
  __syncthreads();
  float4 hv = *(const float4*)&hs[lane << 2];
  const float* xr = Xih + ((size_t)step * B + b) * E;
  // phase 1: 64 outputs per wave
#pragma unroll 4
  for (int i = 0; i < 64; i++) {
    int d = (wave << 6) + i;
    float4 w = *(const float4*)(W_hh + (size_t)d * E + (lane << 2));
    float s = hv.x * w.x + hv.y * w.y + hv.z * w.z + hv.w * w.w;
    s = wave_reduce(s);
    if (lane == 0) {
      float hvn = tanhf(xr[d] + b_hh[d] + s);
      hn[d] = hvn;
      h_g[(size_t)b * E + d] = hvn;
    }
  }
  __syncthreads();
  // phase 2: waves 0-1 -> hVm, waves 2-3 -> hVc, 128 outputs each
  float4 h2 = *(const float4*)&hn[lane << 2];
  const float* Wv = (wave < 2) ? Vm : Vc;
  float* outp = (wave < 2) ? hVm : hVc;
  int d0 = (wave & 1) << 7;
#pragma unroll 4
  for (int i = 0; i < 128; i++) {
    int d = d0 + i;
    float4 w = *(const float4*)(Wv + (size_t)d * E + (lane << 2));
    float s = h2.x * w.x + h2.y * w.y + h2.z * w.z + h2.w * w.w;
    s = wave_reduce(s);
    if (lane == 0) outp[(size_t)b * E + d] = s;
  }
}

// ---------------- energies -> p (noise+sigmoid) and e_c ; one wave per (b,t) ----------
__global__ __launch_bounds__(256) void energy_kernel(
    const float* __restrict__ encWm, const float* __restrict__ encWc,
    const float* __restrict__ hVm, const float* __restrict__ hVc,
    const float* __restrict__ w_effm, const float* __restrict__ w_effc,
    const float* __restrict__ vbm, const float* __restrict__ rmp,
    const float* __restrict__ vbc, const float* __restrict__ rcp,
    const float* __restrict__ noise, float* __restrict__ p_buf,
    float* __restrict__ ec_buf, int step)
{
  const int wave = threadIdx.x >> 6, lane = threadIdx.x & 63;
  const int idx = blockIdx.x * 4 + wave;       // idx = b*T_ENC + t
  const int b = idx >> 9;
  const int a0 = lane << 2;
  float4 em  = *(const float4*)(encWm + (size_t)idx * E + a0);
  float4 ecv = *(const float4*)(encWc + (size_t)idx * E + a0);
  float4 hm  = *(const float4*)(hVm + (size_t)b * E + a0);
  float4 hc  = *(const float4*)(hVc + (size_t)b * E + a0);
  float4 wm  = *(const float4*)(w_effm + a0);
  float4 wc  = *(const float4*)(w_effc + a0);
  float sm = wm.x * tanhf(em.x + hm.x) + wm.y * tanhf(em.y + hm.y)
           + wm.z * tanhf(em.z + hm.z) + wm.w * tanhf(em.w + hm.w);
  float sc = wc.x * tanhf(ecv.x + hc.x) + wc.y * tanhf(ecv.y + hc.y)
           + wc.z * tanhf(ecv.z + hc.z) + wc.w * tanhf(ecv.w + hc.w);
  sm = wave_reduce(sm);
  sc = wave_reduce(sc);
  if (lane == 0) {
    float e_m = sm + vbm[0] + rmp[0];
    float z = e_m + noise[(size_t)step * (B * T_ENC) + idx];
    p_buf[idx] = 1.0f / (1.0f + expf(-z));
    ec_buf[idx] = sc + vbc[0] + rcp[0];
  }
}

// ---------------- inclusive Hillis-Steele scan over 512 (512 threads) ----------------
__device__ __forceinline__ float scan512(float v, float* a, float* b, int tid)
{
  __syncthreads();
  a[tid] = v;
  __syncthreads();
  float* src = a; float* dst = b;
#pragma unroll
  for (int off = 1; off < 512; off <<= 1) {
    float x = src[tid];
    if (tid >= off) x += src[tid - off];
    dst[tid] = x;
    __syncthreads();
    float* t = src; src = dst; dst = t;
  }
  return src[tid];
}

// ---------------- alpha scan + beta + context + combine -> attn (bf16) ; one block per b ----
__global__ __launch_bounds__(512) void alpha_kernel(
    const float* __restrict__ p_buf, const float* __restrict__ ec_buf,
    float* __restrict__ alpha_g, const float* __restrict__ enc,
    const float* __restrict__ h_g, const float* __restrict__ W_comb,
    unsigned short* __restrict__ attn_bf, int step)
{
  __shared__ float sa[512], sb[512], arr[512], c2S[512], betaS[512], cs[512];
  const int b = blockIdx.x, tid = threadIdx.x;
  const size_t base = (size_t)b * T_ENC + tid;
  float p = p_buf[base];
  float ec = ec_buf[base];
  float aprev = alpha_g[base];

  // exclusive safe cumprod of (1-p)
  float lg = logf(fminf(fmaxf(1.0f - p, 1e-10f), 1.0f));
  float incl = scan512(lg, sa, sb, tid);
  arr[tid] = incl;
  __syncthreads();
  float excl = (tid == 0) ? 0.0f : arr[tid - 1];
  float cp = expf(excl);

  // alpha = p * cp * cumsum(alpha_prev / clip(cp))
  float ao = aprev / fminf(fmaxf(cp, 1e-10f), 1.0f);
  float s2 = scan512(ao, sa, sb, tid);
  float alpha_new = p * cp * s2;
  alpha_g[base] = alpha_new;

  // block max of e_c
  __syncthreads();
  sa[tid] = ec;
  __syncthreads();
  for (int off = 256; off >= 1; off >>= 1) {
    if (tid < off) sa[tid] = fmaxf(sa[tid], sa[tid + off]);
    __syncthreads();
  }
  float mx = sa[0];
  float eu = expf(ec - mx);

  // denom = clip(moving_sum(eu, 7, 0))
  float c1 = scan512(eu, sa, sb, tid);
  arr[tid] = c1;
  __syncthreads();
  float denom = c1 - ((tid >= 8) ? arr[tid - 8] : 0.0f);
  denom = fmaxf(denom, 1e-10f);

  // beta = eu * moving_sum(alpha/denom, 0, 7)
  float r = alpha_new / denom;
  float c2 = scan512(r, sa, sb, tid);
  c2S[tid] = c2;
  __syncthreads();
  int hi = (tid + 7 < 511) ? (tid + 7) : 511;
  float ms2 = c2S[hi] - ((tid > 0) ? c2S[tid - 1] : 0.0f);
  betaS[tid] = eu * ms2;
  __syncthreads();

  // context[e] = sum_t beta[t]*enc[b,t,e] (t split over two halves, 4 chains each)
  const int e = tid & 255, half = tid >> 8;
  const float* ep = enc + ((size_t)b * T_ENC + (half << 8)) * E + e;
  const float* bp = &betaS[half << 8];
  float a0 = 0.f, a1 = 0.f, a2 = 0.f, a3 = 0.f;
#pragma unroll 2
  for (int t = 0; t < 256; t += 4) {
    a0 += bp[t]     * ep[(size_t)t * E];
    a1 += bp[t + 1] * ep[(size_t)(t + 1) * E];
    a2 += bp[t + 2] * ep[(size_t)(t + 2) * E];
    a3 += bp[t + 3] * ep[(size_t)(t + 3) * E];
  }
  sa[tid] = (a0 + a1) + (a2 + a3);
  __syncthreads();
  if (half == 0) cs[e] = sa[e] + sa[e + 256];           // cs[0:256] = context
  else           cs[256 + e] = h_g[(size_t)b * E + e];  // cs[256:512] = h
  __syncthreads();

  // combine: attn[d] = tanh([ctx,h] . W_comb[d,:]) ; wave-split-K, 8 waves x 32 outputs
  const int wave = tid >> 6, lane = tid & 63;
  float4 cv0 = *(const float4*)&cs[lane << 3];
  float4 cv1 = *(const float4*)&cs[(lane << 3) + 4];
#pragma unroll 4
  for (int i = 0; i < 32; i++) {
    int d = (wave << 5) + i;
    const float* wr = W_comb + (size_t)d * (2 * E) + (lane << 3);
    float4 w0 = *(const float4*)wr;
    float4 w1 = *(const float4*)(wr + 4);
    float s = cv0.x * w0.x + cv0.y * w0.y + cv0.z * w0.z + cv0.w * w0.w
            + cv1.x * w1.x + cv1.y * w1.y + cv1.z * w1.z + cv1.w * w1.w;
    s = wave_reduce(s);
    if (lane == 0)
      attn_bf[((size_t)b * T_DEC + step) * E + d] = f2bf(tanhf(s));
  }
}

// ---------------- projection: out[r,n] = attn[r,:] . W_proj[n,:] + b_proj[n] (bf16 MFMA) ----
// block = 256 thr (4 waves); block tile 64(M) x 64(N); wave w: rows [w*16, w*16+16)
__global__ __launch_bounds__(256) void proj_mfma(
    const unsigned short* __restrict__ A, const unsigned short* __restrict__ Bw,
    const float* __restrict__ bias, float* __restrict__ Y)
{
  const int wave = threadIdx.x >> 6, lane = threadIdx.x & 63;
  const int m = lane & 15, q = lane >> 4;
  const int row0 = blockIdx.y * 64 + wave * 16;
  const int col0 = blockIdx.x * 64;
  floatx4 acc0 = {0.f, 0.f, 0.f, 0.f}, acc1 = acc0, acc2 = acc0, acc3 = acc0;
  const unsigned short* ar = A + (size_t)(row0 + m) * E + q * 8;
  const unsigned short* br = Bw + (size_t)(col0 + m) * E + q * 8;
#pragma unroll
  for (int k0 = 0; k0 < E; k0 += 32) {
    short8 af = *(const short8*)(ar + k0);
    short8 b0 = *(const short8*)(br + k0);
    short8 b1 = *(const short8*)(br + (size_t)16 * E + k0);
    short8 b2 = *(const short8*)(br + (size_t)32 * E + k0);
    short8 b3 = *(const short8*)(br + (size_t)48 * E + k0);
    acc0 = __builtin_amdgcn_mfma_f32_16x16x32_bf16(af, b0, acc0, 0, 0, 0);
    acc1 = __builtin_amdgcn_mfma_f32_16x16x32_bf16(af, b1, acc1, 0, 0, 0);
    acc2 = __builtin_amdgcn_mfma_f32_16x16x32_bf16(af, b2, acc2, 0, 0, 0);
    acc3 = __builtin_amdgcn_mfma_f32_16x16x32_bf16(af, b3, acc3, 0, 0, 0);
  }
  // C/D: col = lane&15, row = (lane>>4)*4 + reg   [m89/m91 verified mapping]
#pragma unroll
  for (int r = 0; r < 4; r++) {
    const size_t rw = (size_t)(row0 + q * 4 + r) * VOCAB;
    Y[rw + col0 +  0 + m] = acc0[r] + bias[col0 +  0 + m];
    Y[rw + col0 + 16 + m] = acc1[r] + bias[col0 + 16 + m];
    Y[rw + col0 + 32 + m] = acc2[r] + bias[col0 + 32 + m];
    Y[rw + col0 + 48 + m] = acc3[r] + bias[col0 + 48 + m];
  }
}

// ---------------- launch ----------------
extern "C" void kernel_launch(void* const* d_in, const int* in_sizes, int n_in,
                              void* d_out, int out_size, void* d_ws, size_t ws_size,
                              hipStream_t stream)
{
  (void)in_sizes; (void)n_in; (void)out_size; (void)ws_size;
  const float* enc    = (const float*)d_in[0];
  const int*   dec    = (const int*)d_in[1];
  const float* h0     = (const float*)d_in[2];
  const float* noise  = (const float*)d_in[3];
  const float* emb    = (const float*)d_in[4];
  const float* W_ih   = (const float*)d_in[5];
  const float* b_ih   = (const float*)d_in[6];
  const float* W_hh   = (const float*)d_in[7];
  const float* b_hh   = (const float*)d_in[8];
  const float* Wm     = (const float*)d_in[9];
  const float* Vm     = (const float*)d_in[10];
  const float* bm     = (const float*)d_in[11];
  const float* vvm    = (const float*)d_in[12];
  const float* gm     = (const float*)d_in[13];
  const float* vbm    = (const float*)d_in[14];
  const float* rmp    = (const float*)d_in[15];
  const float* Wc     = (const float*)d_in[16];
  const float* Vc     = (const float*)d_in[17];
  const float* bc     = (const float*)d_in[18];
  const float* vvc    = (const float*)d_in[19];
  const float* gc     = (const float*)d_in[20];
  const float* vbc    = (const float*)d_in[21];
  const float* rcp    = (const float*)d_in[22];
  const float* W_comb = (const float*)d_in[23];
  const float* W_proj = (const float*)d_in[24];
  const float* b_proj = (const float*)d_in[25];

  float* ws = (float*)d_ws;
  float* encWm  = ws + OFF_ENCWM;
  float* encWc  = ws + OFF_ENCWC;
  float* w_effm = ws + OFF_WEFFM;
  float* w_effc = ws + OFF_WEFFC;
  float* h_g    = ws + OFF_H;
  float* hVm    = ws + OFF_HVM;
  float* hVc    = ws + OFF_HVC;
  float* p_buf  = ws + OFF_P;
  float* ec_buf = ws + OFF_EC;
  float* alpha  = ws + OFF_ALPHA;
  float* Xih    = ws + OFF_XIH;
  unsigned short* attn_bf = (unsigned short*)(ws + OFF_ATTNB);
  unsigned short* Wp_bf   = (unsigned short*)(ws + OFF_WPBF);
  float* out    = (float*)d_out;
  float* embX   = out;   // scratch: d_out's first 1 MB, consumed before projection writes

  weff_kernel<<<2, 256, 0, stream>>>(vvm, gm, w_effm, vvc, gc, w_effc);
  init_kernel<<<64, 256, 0, stream>>>(alpha, h_g, h0);
  gather_emb<<<T_DEC * B, 256, 0, stream>>>(dec, emb, embX);
  // Xih = embX @ W_ih.T + b_ih  (b_hh added inside rnn_step)
  gemm_xwt<<<dim3(E / 64, (T_DEC * B) / 64), 256, 0, stream>>>(embX, W_ih, b_ih, Xih,
                                                               T_DEC * B, E, E);
  // step-invariant: encW = enc @ W.T + b
  gemm_xwt<<<dim3(E / 64, (B * T_ENC) / 64), 256, 0, stream>>>(enc, Wm, bm, encWm, B * T_ENC, E, E);
  gemm_xwt<<<dim3(E / 64, (B * T_ENC) / 64), 256, 0, stream>>>(enc, Wc, bc, encWc, B * T_ENC, E, E);
  // W_proj -> bf16 (32000*256 / 1024 per block)
  cvt_bf16<<<(VOCAB * E) / 1024, 256, 0, stream>>>(W_proj, Wp_bf);

  for (int step = 0; step < T_DEC; step++) {
    rnn_step<<<B, 256, 0, stream>>>(Xih, W_hh, b_hh, Vm, Vc, h_g, hVm, hVc, step);
    energy_kernel<<<(B * T_ENC) / 4, 256, 0, stream>>>(encWm, encWc, hVm, hVc,
                                                       w_effm, w_effc, vbm, rmp, vbc, rcp,
                                                       noise, p_buf, ec_buf, step);
    alpha_kernel<<<B, 512, 0, stream>>>(p_buf, ec_buf, alpha, enc, h_g, W_comb, attn_bf, step);
  }

  // deferred vocab projection via bf16 MFMA
  proj_mfma<<<dim3(VOCAB / 64, (T_DEC * B) / 64), 256, 0, stream>>>(attn_bf, Wp_bf, b_proj, out);
}

// Round 3
// 2375.389 us; speedup vs baseline: 2.0761x; 2.0761x over previous
//
#include <hip/hip_runtime.h>
#include <cstddef>

#define B 32
#define T_ENC 512
#define T_DEC 32
#define E 256
#define VOCAB 32000
#define SOS 1

typedef __attribute__((ext_vector_type(8))) short short8;   // 8 x bf16
typedef __attribute__((ext_vector_type(4))) float floatx4;  // MFMA acc

// ---------------- workspace layout (float offsets) ----------------
static const size_t OFF_ENCWM  = 0;                                    // 4194304
static const size_t OFF_ENCWC  = OFF_ENCWM + (size_t)B * T_ENC * E;    // 4194304
static const size_t OFF_WEFFM  = OFF_ENCWC + (size_t)B * T_ENC * E;    // 256
static const size_t OFF_WEFFC  = OFF_WEFFM + E;                        // 256
static const size_t OFF_BSUM   = OFF_WEFFC + E;                        // 256
static const size_t OFF_XIH    = OFF_BSUM + E;                         // 262144
static const size_t OFF_WHHT   = OFF_XIH + (size_t)T_DEC * B * E;      // 65536
static const size_t OFF_VMT    = OFF_WHHT + (size_t)E * E;             // 65536
static const size_t OFF_VCT    = OFF_VMT + (size_t)E * E;              // 65536
static const size_t OFF_WCOMBT = OFF_VCT + (size_t)E * E;              // 131072
static const size_t OFF_ATTNB  = OFF_WCOMBT + (size_t)2 * E * E;       // 131072 floats (ushort x2)
static const size_t OFF_WPBF   = OFF_ATTNB + (size_t)T_DEC * B * E / 2;// 4096000 floats (ushort x2)
// total ~13.2M floats ~= 52.8 MB

// ---------------- helpers ----------------
__device__ __forceinline__ float ftanh(float x) {
  float ax = __builtin_fabsf(x);
  float e  = __expf(-2.f * ax);
  float r  = (1.f - e) * __builtin_amdgcn_rcpf(1.f + e);
  return __builtin_copysignf(r, x);
}

__device__ __forceinline__ float fsigmoid(float z) {
  return __builtin_amdgcn_rcpf(1.f + __expf(-z));
}

__device__ __forceinline__ float wredsum(float s) {
  s += __shfl_xor(s, 1, 64);  s += __shfl_xor(s, 2, 64);  s += __shfl_xor(s, 4, 64);
  s += __shfl_xor(s, 8, 64);  s += __shfl_xor(s, 16, 64); s += __shfl_xor(s, 32, 64);
  return s;
}

__device__ __forceinline__ float wredmax(float s) {
  s = fmaxf(s, __shfl_xor(s, 1, 64));  s = fmaxf(s, __shfl_xor(s, 2, 64));
  s = fmaxf(s, __shfl_xor(s, 4, 64));  s = fmaxf(s, __shfl_xor(s, 8, 64));
  s = fmaxf(s, __shfl_xor(s, 16, 64)); s = fmaxf(s, __shfl_xor(s, 32, 64));
  return s;
}

__device__ __forceinline__ unsigned short f2bf(float f) {
  unsigned int u = __float_as_uint(f);
  u = (u + 0x7fffu + ((u >> 16) & 1u)) >> 16;   // RNE
  return (unsigned short)u;
}

// Inclusive scan over 512 values held by tid<512; ALL 1024 threads must call.
__device__ __forceinline__ float scan512(float v, int tid, volatile float* wtot)
{
  const int lane = tid & 63, w = tid >> 6;
#pragma unroll
  for (int off = 1; off < 64; off <<= 1) {
    float y = __shfl_up(v, off, 64);
    if (lane >= off) v += y;
  }
  __syncthreads();                    // protect wtot reuse across consecutive scans
  if (tid < 512 && lane == 63) wtot[w] = v;
  __syncthreads();
  float add = 0.f;
#pragma unroll
  for (int i = 0; i < 7; i++) if (i < w) add += wtot[i];
  return v + add;
}

// ---------------- w_eff = (g/||vv||)*vv ----------------
__global__ __launch_bounds__(256) void weff_kernel(
    const float* __restrict__ vvm, const float* __restrict__ gm, float* __restrict__ w_effm,
    const float* __restrict__ vvc, const float* __restrict__ gc, float* __restrict__ w_effc)
{
  const float* vv = blockIdx.x ? vvc : vvm;
  const float* g  = blockIdx.x ? gc  : gm;
  float* out      = blockIdx.x ? w_effc : w_effm;
  __shared__ float red[256];
  int tid = threadIdx.x;
  float v = vv[tid];
  red[tid] = v * v;
  __syncthreads();
  for (int off = 128; off > 0; off >>= 1) {
    if (tid < off) red[tid] += red[tid + off];
    __syncthreads();
  }
  float norm = sqrtf(red[0]);
  out[tid] = (g[0] / norm) * v;
}

// ---------------- bsum = b_ih + b_hh ----------------
__global__ __launch_bounds__(256) void prep_bias(
    const float* __restrict__ b_ih, const float* __restrict__ b_hh, float* __restrict__ bsum)
{
  bsum[threadIdx.x] = b_ih[threadIdx.x] + b_hh[threadIdx.x];
}

// ---------------- out[c*R + r] = in[r*C + c] ----------------
__global__ __launch_bounds__(256) void transpose_k(
    const float* __restrict__ in, float* __restrict__ out, int R, int C)
{
  __shared__ float tl[32][33];
  const int tx = threadIdx.x & 31, ty = threadIdx.x >> 5;
  const int c0 = blockIdx.x * 32, r0 = blockIdx.y * 32;
#pragma unroll
  for (int k = 0; k < 4; k++)
    tl[ty + 8 * k][tx] = in[(size_t)(r0 + ty + 8 * k) * C + c0 + tx];
  __syncthreads();
#pragma unroll
  for (int k = 0; k < 4; k++)
    out[(size_t)(c0 + ty + 8 * k) * R + r0 + tx] = tl[tx][ty + 8 * k];
}

// ---------------- gather embeddings: embX[r,:] = emb[tok(r)], r = step*B+b ----------
__global__ __launch_bounds__(256) void gather_emb(
    const int* __restrict__ dec, const float* __restrict__ emb, float* __restrict__ embX)
{
  int r = blockIdx.x, d = threadIdx.x;
  int s = r >> 5, b = r & 31;
  int tok = (s == 0) ? SOS : dec[b * T_DEC + s - 1];
  embX[(size_t)r * E + d] = emb[(size_t)tok * E + d];
}

// ---------------- f32 -> bf16 convert (4 per thread) ----------------
__global__ __launch_bounds__(256) void cvt_bf16(
    const float* __restrict__ src, unsigned short* __restrict__ dst)
{
  size_t i = ((size_t)blockIdx.x * 256 + threadIdx.x) * 4;
  float4 v = *(const float4*)(src + i);
  ushort4 o;
  o.x = f2bf(v.x); o.y = f2bf(v.y); o.z = f2bf(v.z); o.w = f2bf(v.w);
  *(ushort4*)(dst + i) = o;
}

// ---------------- Y[r,n] = bias[n] + sum_k A[r,k]*W[n,k] (f32 VALU GEMM) ----------------
__global__ __launch_bounds__(256) void gemm_xwt(
    const float* __restrict__ A, const float* __restrict__ W,
    const float* __restrict__ bias, float* __restrict__ Y,
    int M, int N, int K)
{
  __shared__ float As[64][68];
  __shared__ float Ws[64][68];
  const int tid = threadIdx.x;
  const int tx = tid & 15, ty = tid >> 4;
  const int row0 = blockIdx.y * 64, col0 = blockIdx.x * 64;
  float acc[4][4];
#pragma unroll
  for (int i = 0; i < 4; i++)
#pragma unroll
    for (int j = 0; j < 4; j++) acc[i][j] = 0.f;

  for (int k0 = 0; k0 < K; k0 += 64) {
#pragma unroll
    for (int s = 0; s < 4; s++) {
      int i = (s << 4) + ty;
      int j = tx << 2;
      float4 av = *(const float4*)(A + (size_t)(row0 + i) * K + k0 + j);
      As[j][i] = av.x; As[j + 1][i] = av.y; As[j + 2][i] = av.z; As[j + 3][i] = av.w;
      float4 wv = *(const float4*)(W + (size_t)(col0 + i) * K + k0 + j);
      Ws[j][i] = wv.x; Ws[j + 1][i] = wv.y; Ws[j + 2][i] = wv.z; Ws[j + 3][i] = wv.w;
    }
    __syncthreads();
#pragma unroll
    for (int kk = 0; kk < 64; kk++) {
      const float4 af = *(const float4*)&As[kk][ty << 2];
      const float4 bf = *(const float4*)&Ws[kk][tx << 2];
      acc[0][0] += af.x * bf.x; acc[0][1] += af.x * bf.y; acc[0][2] += af.x * bf.z; acc[0][3] += af.x * bf.w;
      acc[1][0] += af.y * bf.x; acc[1][1] += af.y * bf.y; acc[1][2] += af.y * bf.z; acc[1][3] += af.y * bf.w;
      acc[2][0] += af.z * bf.x; acc[2][1] += af.z * bf.y; acc[2][2] += af.z * bf.z; acc[2][3] += af.z * bf.w;
      acc[3][0] += af.w * bf.x; acc[3][1] += af.w * bf.y; acc[3][2] += af.w * bf.z; acc[3][3] += af.w * bf.w;
    }
    __syncthreads();
  }
  const float4 bv = *(const float4*)(bias + col0 + (tx << 2));
#pragma unroll
  for (int i = 0; i < 4; i++) {
    float4 o;
    o.x = acc[i][0] + bv.x; o.y = acc[i][1] + bv.y;
    o.z = acc[i][2] + bv.z; o.w = acc[i][3] + bv.w;
    *(float4*)(Y + (size_t)(row0 + (ty << 2) + i) * N + col0 + (tx << 2)) = o;
  }
}

// ---------------- persistent decode: all 32 steps, one block per batch element ----------
__global__ __launch_bounds__(1024) void decode_kernel(
    const float* __restrict__ Xih, const float* __restrict__ W_hhT,
    const float* __restrict__ VmT, const float* __restrict__ VcT,
    const float* __restrict__ encWm, const float* __restrict__ encWc,
    const float* __restrict__ w_effm, const float* __restrict__ w_effc,
    const float* __restrict__ vbm, const float* __restrict__ rmp,
    const float* __restrict__ vbc, const float* __restrict__ rcp_,
    const float* __restrict__ noise, const float* __restrict__ enc,
    const float* __restrict__ h0, const float* __restrict__ W_combT,
    unsigned short* __restrict__ attn_bf)
{
  __shared__ float h_s[E], hVm_s[E], hVc_s[E];
  __shared__ float p_s[T_ENC], ec_s[T_ENC], alpha_s[T_ENC], beta_s[T_ENC];
  __shared__ float noise_s[T_ENC], tmp_s[T_ENC], c2_s[T_ENC], cs[2 * E];
  __shared__ float red[1024];
  __shared__ float wtot[8], wmax[8];

  const int b = blockIdx.x, tid = threadIdx.x;
  const int lane = tid & 63, w = tid >> 6;

  if (tid < E) h_s[tid] = h0[(size_t)b * E + tid];
  if (tid < T_ENC) alpha_s[tid] = (tid == 0) ? 1.f : 0.f;
  const float embias = vbm[0] + rmp[0];
  const float ecbias = vbc[0] + rcp_[0];
  const float4 wm4 = *(const float4*)(w_effm + lane * 4);
  const float4 wc4 = *(const float4*)(w_effc + lane * 4);
  __syncthreads();

  for (int step = 0; step < T_DEC; ++step) {
    // ---- A: h = tanh(Xih_tot + W_hh h)   (Xih_tot includes b_ih + b_hh)
    {
      const int c = tid >> 8, d = tid & 255;
      const float* wp = W_hhT + d;
      const int k0 = c * 64;
      float acc = 0.f;
#pragma unroll 4
      for (int j = 0; j < 64; j += 4) {
        float4 hh = *(const float4*)&h_s[k0 + j];
        acc += hh.x * wp[(k0 + j) * E]     + hh.y * wp[(k0 + j + 1) * E]
             + hh.z * wp[(k0 + j + 2) * E] + hh.w * wp[(k0 + j + 3) * E];
      }
      red[tid] = acc;
      __syncthreads();
      if (tid < E) {
        float s = red[tid] + red[256 + tid] + red[512 + tid] + red[768 + tid]
                + Xih[((size_t)step * B + b) * E + tid];
        h_s[tid] = ftanh(s);
      }
      __syncthreads();
    }
    // ---- B: hVm = Vm h, hVc = Vc h ; stage noise row
    {
      const int g = tid >> 8, d = tid & 255;
      const float* wp = ((g < 2) ? VmT : VcT) + d;
      const int k0 = (g & 1) * 128;
      float acc = 0.f;
#pragma unroll 4
      for (int j = 0; j < 128; j += 4) {
        float4 hh = *(const float4*)&h_s[k0 + j];
        acc += hh.x * wp[(k0 + j) * E]     + hh.y * wp[(k0 + j + 1) * E]
             + hh.z * wp[(k0 + j + 2) * E] + hh.w * wp[(k0 + j + 3) * E];
      }
      red[tid] = acc;
      __syncthreads();
      if (tid < 256)      hVm_s[tid] = red[tid] + red[256 + tid];
      else if (tid < 512) hVc_s[tid - 256] = red[512 + (tid - 256)] + red[768 + (tid - 256)];
      else                noise_s[tid - 512] = noise[((size_t)step * B + b) * T_ENC + (tid - 512)];
      __syncthreads();
    }
    // ---- C: energies -> p, e_c  (wave w handles t in [w*32, w*32+32))
    {
      const float4 hm4 = *(const float4*)&hVm_s[lane * 4];
      const float4 hc4 = *(const float4*)&hVc_s[lane * 4];
#pragma unroll 2
      for (int i = 0; i < 32; ++i) {
        const int t = w * 32 + i;
        const float4 em4 = *(const float4*)(encWm + (((size_t)b * T_ENC + t) << 8) + lane * 4);
        const float4 ec4 = *(const float4*)(encWc + (((size_t)b * T_ENC + t) << 8) + lane * 4);
        float sm = wm4.x * ftanh(em4.x + hm4.x) + wm4.y * ftanh(em4.y + hm4.y)
                 + wm4.z * ftanh(em4.z + hm4.z) + wm4.w * ftanh(em4.w + hm4.w);
        float sc = wc4.x * ftanh(ec4.x + hc4.x) + wc4.y * ftanh(ec4.y + hc4.y)
                 + wc4.z * ftanh(ec4.z + hc4.z) + wc4.w * ftanh(ec4.w + hc4.w);
        sm = wredsum(sm);
        sc = wredsum(sc);
        if (lane == 0) {
          p_s[t]  = fsigmoid(sm + embias + noise_s[t]);
          ec_s[t] = sc + ecbias;
        }
      }
      __syncthreads();
    }
    // ---- D: alpha recurrence + chunkwise beta (scans)
    {
      const bool val = tid < T_ENC;
      const int t = tid;
      float p     = val ? p_s[t] : 0.f;
      float aprev = val ? alpha_s[t] : 0.f;
      float ec    = val ? ec_s[t] : -1e30f;

      float omp = fminf(fmaxf(1.f - p, 1e-10f), 1.f);
      float lg  = val ? __logf(omp) : 0.f;
      float incl = scan512(lg, tid, wtot);
      float cp  = __expf(incl - lg);                     // exclusive cumprod
      float cpc = fminf(fmaxf(cp, 1e-10f), 1.f);
      float ao  = val ? aprev * __builtin_amdgcn_rcpf(cpc) : 0.f;
      float s2  = scan512(ao, tid, wtot);
      float alpha_new = p * cp * s2;
      if (val) alpha_s[t] = alpha_new;

      float mxw = wredmax(ec);
      if (val && lane == 0) wmax[w] = mxw;
      __syncthreads();
      float mx = wmax[0];
#pragma unroll
      for (int i = 1; i < 8; i++) mx = fmaxf(mx, wmax[i]);

      float eu = val ? __expf(ec - mx) : 0.f;
      float c1 = scan512(eu, tid, wtot);
      if (val) tmp_s[t] = c1;
      __syncthreads();
      float denom = val ? (c1 - ((t >= 8) ? tmp_s[t - 8] : 0.f)) : 1.f;
      denom = fmaxf(denom, 1e-10f);
      float r = val ? alpha_new * __builtin_amdgcn_rcpf(denom) : 0.f;
      float c2 = scan512(r, tid, wtot);
      if (val) c2_s[t] = c2;
      __syncthreads();
      if (val) {
        int hi = (t + 7 < T_ENC - 1) ? (t + 7) : (T_ENC - 1);
        float ms2 = c2_s[hi] - ((t > 0) ? c2_s[t - 1] : 0.f);
        beta_s[t] = eu * ms2;
      }
      __syncthreads();
    }
    // ---- E: context[e] = sum_t beta[t] * enc[b,t,e]
    {
      const int c = tid >> 8, e = tid & 255;
      const float* ep = enc + ((size_t)b * T_ENC + c * 128) * E + e;
      float acc = 0.f;
#pragma unroll 4
      for (int t2 = 0; t2 < 128; ++t2)
        acc += beta_s[c * 128 + t2] * ep[(size_t)t2 * E];
      red[tid] = acc;
      __syncthreads();
      if (tid < 256)      cs[tid] = red[tid] + red[256 + tid] + red[512 + tid] + red[768 + tid];
      else if (tid < 512) cs[tid] = h_s[tid - 256];
      __syncthreads();
    }
    // ---- F: attn = tanh([ctx,h] @ W_comb.T) -> bf16
    {
      const int c = tid >> 8, d = tid & 255;
      const float* wp = W_combT + d;
      const int k0 = c * 128;
      float acc = 0.f;
#pragma unroll 4
      for (int j = 0; j < 128; j += 4) {
        float4 cc4 = *(const float4*)&cs[k0 + j];
        acc += cc4.x * wp[(k0 + j) * E]     + cc4.y * wp[(k0 + j + 1) * E]
             + cc4.z * wp[(k0 + j + 2) * E] + cc4.w * wp[(k0 + j + 3) * E];
      }
      red[tid] = acc;
      __syncthreads();
      if (tid < 256) {
        float s = red[tid] + red[256 + tid] + red[512 + tid] + red[768 + tid];
        attn_bf[((size_t)b * T_DEC + step) * E + tid] = f2bf(ftanh(s));
      }
      __syncthreads();
    }
  }
}

// ---------------- projection: out = attn @ W_proj.T + b_proj (bf16 MFMA, LDS-staged stores)
__global__ __launch_bounds__(256) void proj_mfma(
    const unsigned short* __restrict__ A, const unsigned short* __restrict__ Bw,
    const float* __restrict__ bias, float* __restrict__ Y)
{
  __shared__ float tile[64][68];
  const int tid = threadIdx.x;
  const int wave = tid >> 6, lane = tid & 63;
  const int m = lane & 15, q = lane >> 4;
  const int rowa = blockIdx.y * 64 + wave * 16;
  const int col0 = blockIdx.x * 64;
  floatx4 acc0 = {0.f, 0.f, 0.f, 0.f}, acc1 = acc0, acc2 = acc0, acc3 = acc0;
  const unsigned short* ar = A + (size_t)(rowa + m) * E + q * 8;
  const unsigned short* br = Bw + (size_t)(col0 + m) * E + q * 8;
#pragma unroll
  for (int k0 = 0; k0 < E; k0 += 32) {
    short8 af = *(const short8*)(ar + k0);
    short8 b0 = *(const short8*)(br + k0);
    short8 b1 = *(const short8*)(br + (size_t)16 * E + k0);
    short8 b2 = *(const short8*)(br + (size_t)32 * E + k0);
    short8 b3 = *(const short8*)(br + (size_t)48 * E + k0);
    acc0 = __builtin_amdgcn_mfma_f32_16x16x32_bf16(af, b0, acc0, 0, 0, 0);
    acc1 = __builtin_amdgcn_mfma_f32_16x16x32_bf16(af, b1, acc1, 0, 0, 0);
    acc2 = __builtin_amdgcn_mfma_f32_16x16x32_bf16(af, b2, acc2, 0, 0, 0);
    acc3 = __builtin_amdgcn_mfma_f32_16x16x32_bf16(af, b3, acc3, 0, 0, 0);
  }
  // C/D: col = lane&15, row = (lane>>4)*4 + reg — stage into LDS tile
  const int rl = wave * 16 + q * 4;
#pragma unroll
  for (int r = 0; r < 4; r++) {
    tile[rl + r][ 0 + m] = acc0[r];
    tile[rl + r][16 + m] = acc1[r];
    tile[rl + r][32 + m] = acc2[r];
    tile[rl + r][48 + m] = acc3[r];
  }
  __syncthreads();
  // full-line coalesced stores: each thread writes 16 consecutive floats of one row
  const int row = tid >> 2, seg = tid & 3;
  const size_t yb = ((size_t)blockIdx.y * 64 + row) * VOCAB + col0;
#pragma unroll
  for (int u = 0; u < 4; u++) {
    int cc = seg * 16 + u * 4;
    float4 v = *(const float4*)&tile[row][cc];
    float4 bb = *(const float4*)(bias + col0 + cc);
    v.x += bb.x; v.y += bb.y; v.z += bb.z; v.w += bb.w;
    *(float4*)(Y + yb + cc) = v;
  }
}

// ---------------- launch ----------------
extern "C" void kernel_launch(void* const* d_in, const int* in_sizes, int n_in,
                              void* d_out, int out_size, void* d_ws, size_t ws_size,
                              hipStream_t stream)
{
  (void)in_sizes; (void)n_in; (void)out_size; (void)ws_size;
  const float* enc    = (const float*)d_in[0];
  const int*   dec    = (const int*)d_in[1];
  const float* h0     = (const float*)d_in[2];
  const float* noise  = (const float*)d_in[3];
  const float* emb    = (const float*)d_in[4];
  const float* W_ih   = (const float*)d_in[5];
  const float* b_ih   = (const float*)d_in[6];
  const float* W_hh   = (const float*)d_in[7];
  const float* b_hh   = (const float*)d_in[8];
  const float* Wm     = (const float*)d_in[9];
  const float* Vm     = (const float*)d_in[10];
  const float* bm     = (const float*)d_in[11];
  const float* vvm    = (const float*)d_in[12];
  const float* gm     = (const float*)d_in[13];
  const float* vbm    = (const float*)d_in[14];
  const float* rmp    = (const float*)d_in[15];
  const float* Wc     = (const float*)d_in[16];
  const float* Vc     = (const float*)d_in[17];
  const float* bc     = (const float*)d_in[18];
  const float* vvc    = (const float*)d_in[19];
  const float* gc     = (const float*)d_in[20];
  const float* vbc    = (const float*)d_in[21];
  const float* rcp_   = (const float*)d_in[22];
  const float* W_comb = (const float*)d_in[23];
  const float* W_proj = (const float*)d_in[24];
  const float* b_proj = (const float*)d_in[25];

  float* ws = (float*)d_ws;
  float* encWm   = ws + OFF_ENCWM;
  float* encWc   = ws + OFF_ENCWC;
  float* w_effm  = ws + OFF_WEFFM;
  float* w_effc  = ws + OFF_WEFFC;
  float* bsum    = ws + OFF_BSUM;
  float* Xih     = ws + OFF_XIH;
  float* W_hhT   = ws + OFF_WHHT;
  float* VmT     = ws + OFF_VMT;
  float* VcT     = ws + OFF_VCT;
  float* W_combT = ws + OFF_WCOMBT;
  unsigned short* attn_bf = (unsigned short*)(ws + OFF_ATTNB);
  unsigned short* Wp_bf   = (unsigned short*)(ws + OFF_WPBF);
  float* out  = (float*)d_out;
  float* embX = out;   // scratch in d_out; consumed before decode/proj write it

  weff_kernel<<<2, 256, 0, stream>>>(vvm, gm, w_effm, vvc, gc, w_effc);
  prep_bias<<<1, 256, 0, stream>>>(b_ih, b_hh, bsum);
  transpose_k<<<dim3(8, 8), 256, 0, stream>>>(W_hh, W_hhT, E, E);
  transpose_k<<<dim3(8, 8), 256, 0, stream>>>(Vm, VmT, E, E);
  transpose_k<<<dim3(8, 8), 256, 0, stream>>>(Vc, VcT, E, E);
  transpose_k<<<dim3(16, 8), 256, 0, stream>>>(W_comb, W_combT, E, 2 * E);
  gather_emb<<<T_DEC * B, 256, 0, stream>>>(dec, emb, embX);
  // Xih = embX @ W_ih.T + (b_ih + b_hh)
  gemm_xwt<<<dim3(E / 64, (T_DEC * B) / 64), 256, 0, stream>>>(embX, W_ih, bsum, Xih,
                                                               T_DEC * B, E, E);
  // step-invariant: encW = enc @ W.T + b
  gemm_xwt<<<dim3(E / 64, (B * T_ENC) / 64), 256, 0, stream>>>(enc, Wm, bm, encWm, B * T_ENC, E, E);
  gemm_xwt<<<dim3(E / 64, (B * T_ENC) / 64), 256, 0, stream>>>(enc, Wc, bc, encWc, B * T_ENC, E, E);
  cvt_bf16<<<(VOCAB * E) / 1024, 256, 0, stream>>>(W_proj, Wp_bf);

  // the entire 32-step decode in ONE persistent kernel (one block per batch elem)
  decode_kernel<<<B, 1024, 0, stream>>>(Xih, W_hhT, VmT, VcT, encWm, encWc,
                                        w_effm, w_effc, vbm, rmp, vbc, rcp_,
                                        noise, enc, h0, W_combT, attn_bf);

  // deferred vocab projection via bf16 MFMA
  proj_mfma<<<dim3(VOCAB / 64, (T_DEC * B) / 64), 256, 0, stream>>>(attn_bf, Wp_bf, b_proj, out);
}